// Round 2
// baseline (719.868 us; speedup 1.0000x reference)
//
#include <hip/hip_runtime.h>

namespace {
constexpr int B = 8, C = 128, H = 160, W = 512, D = 64;
constexpr int BLK_J = 128;   // output j columns per block
constexpr int RW    = 192;   // right-feature window cols (j0-64 .. j0+127)
constexpr int CCH   = 32;    // channels per LDS stage
constexpr int LDC   = 40;    // LDS row stride (u16 elems): 32 + 8 pad -> 80B, 16B aligned

typedef unsigned short u16;
typedef u16   u16x8 __attribute__((ext_vector_type(8)));
typedef short s16x8 __attribute__((ext_vector_type(8)));   // MFMA operand ABI (guide-verified)
typedef float f32x4 __attribute__((ext_vector_type(4)));

__device__ inline u16 f2bf(float f) {
    unsigned u = __builtin_bit_cast(unsigned, f);
    u += 0x7fffu + ((u >> 16) & 1u);          // round-to-nearest-even
    return (u16)(u >> 16);
}

__global__ __launch_bounds__(256, 4) void cost_volume_kernel(
    const float* __restrict__ left,
    const float* __restrict__ right,
    float* __restrict__ out)
{
    __shared__ __align__(16) u16 Llds[BLK_J * LDC];
    __shared__ __align__(16) u16 Rlds[RW * LDC];

    const int jb = blockIdx.x;
    const int h  = blockIdx.y;
    const int b  = blockIdx.z;
    const int j0 = jb * BLK_J;

    const int tid  = threadIdx.x;
    const int lane = tid & 63;
    const int wv   = tid >> 6;

    const size_t cstride = (size_t)H * W;     // stride between channels
    const float* lptr = left  + ((size_t)b * C * H + h) * W;
    const float* rptr = right + ((size_t)b * C * H + h) * W;

    // staging decomposition: 64 lanes over j, 4 groups of 8 channels
    const int jj = tid & 63;
    const int cb = (tid >> 6) * 8;

    // mfma lane mapping (16x16x32): A[m=lane&15][k=(lane>>4)*8+i]
    const int row  = lane & 15;
    const int q    = lane >> 4;
    const int koff = q * 8;
    const int t1_0 = wv * 2;       // first j1 tile of this wave
    const int jw   = t1_0 * 16;    // wave's j1 local base

    f32x4 acc[2][5];
    #pragma unroll
    for (int a = 0; a < 2; ++a)
      #pragma unroll
      for (int g = 0; g < 5; ++g)
        acc[a][g] = f32x4{0.f, 0.f, 0.f, 0.f};

    for (int ch = 0; ch < C / CCH; ++ch) {
        const int c0 = ch * CCH;
        if (ch) __syncthreads();

        // ---- stage L: cols [j0, j0+128) x channels [c0, c0+32), LDS layout [col][c] ----
        #pragma unroll
        for (int jsec = 0; jsec < BLK_J; jsec += 64) {
            const int col = jsec + jj;
            const float* p = lptr + (size_t)(c0 + cb) * cstride + (j0 + col);
            u16x8 pk;
            #pragma unroll
            for (int i = 0; i < 8; ++i)
                pk[i] = f2bf(p[i * cstride]);
            *(u16x8*)&Llds[col * LDC + cb] = pk;
        }
        // ---- stage R: col maps to global j = j0 - 64 + col ----
        #pragma unroll
        for (int jsec = 0; jsec < RW; jsec += 64) {
            const int col = jsec + jj;
            const int gj = j0 - 64 + col;
            u16x8 pk;
            if (gj >= 0) {
                const float* p = rptr + (size_t)(c0 + cb) * cstride + gj;
                #pragma unroll
                for (int i = 0; i < 8; ++i)
                    pk[i] = f2bf(p[i * cstride]);
            } else {
                #pragma unroll
                for (int i = 0; i < 8; ++i)
                    pk[i] = 0;
            }
            *(u16x8*)&Rlds[col * LDC + cb] = pk;
        }
        __syncthreads();

        // ---- fragments + MFMA band ----
        u16x8 Af[2], Bf[6];
        Af[0] = *(const u16x8*)&Llds[(jw      + row) * LDC + koff];
        Af[1] = *(const u16x8*)&Llds[(jw + 16 + row) * LDC + koff];
        #pragma unroll
        for (int u = 0; u < 6; ++u)
            Bf[u] = *(const u16x8*)&Rlds[((t1_0 + u) * 16 + row) * LDC + koff];

        #pragma unroll
        for (int a = 0; a < 2; ++a)
          #pragma unroll
          for (int g = 0; g < 5; ++g)
            acc[a][g] = __builtin_amdgcn_mfma_f32_16x16x32_bf16(
                __builtin_bit_cast(s16x8, Af[a]),
                __builtin_bit_cast(s16x8, Bf[a + 4 - g]),
                acc[a][g], 0, 0, 0);
    }

    // ---- epilogue: P[m = q*4+r][n = row] -> out[d = 16g + m - row][j] ----
    const float inv = 1.0f / (float)C;
    float* obase = out + ((size_t)b * D * H + h) * W;
    #pragma unroll
    for (int a = 0; a < 2; ++a) {
      const int t1 = t1_0 + a;
      #pragma unroll
      for (int g = 0; g < 5; ++g) {
        #pragma unroll
        for (int r = 0; r < 4; ++r) {
          const int m = q * 4 + r;
          const int j = j0 + t1 * 16 + m;
          const int d = 16 * g + m - row;     // d = j - j2
          if (d >= 0 && d < D) {
            const float val = (d <= j) ? acc[a][g][r] * inv : 0.0f;
            obase[(size_t)d * cstride + j] = val;
          }
        }
      }
    }
}
} // namespace

extern "C" void kernel_launch(void* const* d_in, const int* in_sizes, int n_in,
                              void* d_out, int out_size, void* d_ws, size_t ws_size,
                              hipStream_t stream)
{
    const float* left  = (const float*)d_in[0];
    const float* right = (const float*)d_in[1];
    float* out = (float*)d_out;
    dim3 grid(W / BLK_J, H, B);   // (4, 160, 8) = 5120 blocks
    cost_volume_kernel<<<grid, 256, 0, stream>>>(left, right, out);
}

// Round 3
// 682.785 us; speedup vs baseline: 1.0543x; 1.0543x over previous
//
#include <hip/hip_runtime.h>

namespace {
constexpr int B = 8, C = 128, H = 160, W = 512, D = 64;
constexpr int BLK_J = 128;   // output j columns per block
constexpr int RW    = 192;   // right window cols (j0-64 .. j0+127)
constexpr int LDC   = 40;    // u16 elems per LDS row (80B, 16B-aligned)
constexpr int PSTR  = 133;   // P epilogue stride in floats (odd -> few bank conflicts)

typedef unsigned short u16;
typedef u16   u16x4 __attribute__((ext_vector_type(4)));
typedef u16   u16x8 __attribute__((ext_vector_type(8)));
typedef short s16x8 __attribute__((ext_vector_type(8)));
typedef float f32x4 __attribute__((ext_vector_type(4)));

__device__ inline u16 f2bf(float f) {
    unsigned u = __builtin_bit_cast(unsigned, f);
    u += 0x7fffu + ((u >> 16) & 1u);          // RNE
    return (u16)(u >> 16);
}

union SmemU {
    struct { __align__(16) u16 L[BLK_J * LDC]; __align__(16) u16 R[RW * LDC]; } s;
    float P[D * PSTR];
};

__global__ __launch_bounds__(256, 4) void cost_volume_kernel(
    const float* __restrict__ left,
    const float* __restrict__ right,
    float* __restrict__ out)
{
    __shared__ SmemU sm;

    const int jb = blockIdx.x;
    const int h  = blockIdx.y;
    const int b  = blockIdx.z;
    const int j0 = jb * BLK_J;

    const int tid  = threadIdx.x;
    const int lane = tid & 63;
    const int wv   = tid >> 6;

    const size_t cstride = (size_t)H * W;
    const float* lptr = left  + ((size_t)b * C * H + h) * W;
    const float* rptr = right + ((size_t)b * C * H + h) * W;

    // ---- staging decomposition (per thread, per 32-channel chunk) ----
    // L and R-partA: 4 float4 loads at channels cq..cq+3, cols jL..jL+3
    // R-partB:       2 float4 loads at channels cp,cp+1, cols jB..jB+3
    const int cq  = (tid >> 5) * 4;         // 0,4,...,28
    const int jL  = (tid & 31) * 4;         // 0..124
    const int cp  = (tid >> 4) * 2;         // 0,2,...,30
    const int jB  = 128 + (tid & 15) * 4;   // 128..188
    // 16B-block XOR swizzle (same function applied by fragment reads)
    const int swL = ((cq >> 3) ^ (tid & 3)) * 8 + ((cq >> 2) & 1) * 4;  // u16 elems
    const int swB = ((cp >> 3) ^ (tid & 3)) * 8 + ((cp >> 1) & 3) * 2;

    // ---- mfma fragment mapping (16x16x32): A[m=lane&15][k=(lane>>4)*8+i] ----
    const int row  = lane & 15;
    const int q    = lane >> 4;
    const int ksw  = (q ^ ((lane >> 2) & 3)) * 8;   // swizzled k-block offset (u16 elems)
    const int t1_0 = wv * 2;
    const int jw   = t1_0 * 16;

    f32x4 acc[2][5];
    #pragma unroll
    for (int a = 0; a < 2; ++a)
      #pragma unroll
      for (int g = 0; g < 5; ++g)
        acc[a][g] = f32x4{0.f, 0.f, 0.f, 0.f};

    f32x4 lv[4], rv[4], bv[2];
    const int gjA = j0 - 64 + jL;           // R-partA global col (may be <0 on jb==0)
    const int gjB = j0 - 64 + jB;           // R-partB global col (always >= 64)

    auto load_chunk = [&](int ch) {
        const size_t cb = (size_t)ch * 32;
        const float* lp = lptr + (cb + cq) * cstride + (j0 + jL);
        #pragma unroll
        for (int i = 0; i < 4; ++i) lv[i] = *(const f32x4*)(lp + i * cstride);
        if (gjA >= 0) {
            const float* rp = rptr + (cb + cq) * cstride + gjA;
            #pragma unroll
            for (int i = 0; i < 4; ++i) rv[i] = *(const f32x4*)(rp + i * cstride);
        } else {
            #pragma unroll
            for (int i = 0; i < 4; ++i) rv[i] = f32x4{0.f, 0.f, 0.f, 0.f};
        }
        const float* bp = rptr + (cb + cp) * cstride + gjB;
        #pragma unroll
        for (int i = 0; i < 2; ++i) bv[i] = *(const f32x4*)(bp + i * cstride);
    };

    auto write_chunk = [&]() {
        #pragma unroll
        for (int jj = 0; jj < 4; ++jj) {
            u16x4 pa, pb;
            #pragma unroll
            for (int i = 0; i < 4; ++i) pa[i] = f2bf(lv[i][jj]);
            *(u16x4*)&sm.s.L[(jL + jj) * LDC + swL] = pa;
            #pragma unroll
            for (int i = 0; i < 4; ++i) pb[i] = f2bf(rv[i][jj]);
            *(u16x4*)&sm.s.R[(jL + jj) * LDC + swL] = pb;
            unsigned pc = (unsigned)f2bf(bv[0][jj]) | ((unsigned)f2bf(bv[1][jj]) << 16);
            *(unsigned*)&sm.s.R[(jB + jj) * LDC + swB] = pc;
        }
    };

    load_chunk(0);
    #pragma unroll
    for (int ch = 0; ch < 4; ++ch) {
        if (ch) __syncthreads();
        write_chunk();
        if (ch < 3) load_chunk(ch + 1);   // prefetch overlaps barrier + MFMA below
        __syncthreads();

        u16x8 Af[2], Bf[6];
        Af[0] = *(const u16x8*)&sm.s.L[(jw      + row) * LDC + ksw];
        Af[1] = *(const u16x8*)&sm.s.L[(jw + 16 + row) * LDC + ksw];
        #pragma unroll
        for (int u = 0; u < 6; ++u)
            Bf[u] = *(const u16x8*)&sm.s.R[((t1_0 + u) * 16 + row) * LDC + ksw];

        #pragma unroll
        for (int a = 0; a < 2; ++a)
          #pragma unroll
          for (int g = 0; g < 5; ++g)
            acc[a][g] = __builtin_amdgcn_mfma_f32_16x16x32_bf16(
                __builtin_bit_cast(s16x8, Af[a]),
                __builtin_bit_cast(s16x8, Bf[a + 4 - g]),
                acc[a][g], 0, 0, 0);
    }

    // ---- epilogue: scatter P into LDS, then coalesced float4 stores ----
    __syncthreads();          // staging LDS -> P overlay
    const float inv = 1.0f / (float)C;
    #pragma unroll
    for (int a = 0; a < 2; ++a) {
      const int t1 = t1_0 + a;
      #pragma unroll
      for (int g = 0; g < 5; ++g) {
        #pragma unroll
        for (int r = 0; r < 4; ++r) {
          const int m  = q * 4 + r;
          const int jl = t1 * 16 + m;
          const int d  = 16 * g + m - row;      // d = j - j2; R zeros handle d>j band
          if ((unsigned)d < (unsigned)D)
            sm.P[d * PSTR + jl] = acc[a][g][r] * inv;
        }
      }
    }
    __syncthreads();

    float* obase = out + (size_t)b * D * H * W + (size_t)h * W;
    #pragma unroll
    for (int s = 0; s < 8; ++s) {
        const int u  = tid + 256 * s;
        const int d  = u >> 5;
        const int j4 = (u & 31) * 4;
        f32x4 v;
        #pragma unroll
        for (int i = 0; i < 4; ++i) v[i] = sm.P[d * PSTR + j4 + i];
        *(f32x4*)(obase + (size_t)d * cstride + j0 + j4) = v;
    }
}
} // namespace

extern "C" void kernel_launch(void* const* d_in, const int* in_sizes, int n_in,
                              void* d_out, int out_size, void* d_ws, size_t ws_size,
                              hipStream_t stream)
{
    const float* left  = (const float*)d_in[0];
    const float* right = (const float*)d_in[1];
    float* out = (float*)d_out;
    dim3 grid(W / BLK_J, H, B);   // (4, 160, 8) = 5120 blocks
    cost_volume_kernel<<<grid, 256, 0, stream>>>(left, right, out);
}